// Round 5
// baseline (149.595 us; speedup 1.0000x reference)
//
#include <hip/hip_runtime.h>
#include <hip/hip_bf16.h>

// Dead-code-eliminated forward (verified: passed, absmax 7.5e-9, fp32 inputs).
// Cross-attention has ONE key/value -> softmax == 1 -> outputs depend only on:
//   ctx  = context_batch @ ctx_w + ctx_b          (2 -> 512)
//   v    = ctx @ ca_wv + ca_bv                    (512x512)
//   last = v @ ca_wo + ca_bo                      (512x512)
//   pred = last @ pred_w[sid] + pred_b[sid]; act likewise (512x64 each)
//
// Round-4: single dispatch. The 3-kernel version spent ~2/3 of its ~27us on
// inter-dispatch gaps. Grid-wide sync via init-free flag barriers: d_ws is
// poisoned to 0xAA before every launch, so a fresh flag word != MAGIC; each
// block release-stores MAGIC (agent scope -> L2 writeback across XCDs), all
// blocks acquire-poll all 64 flags. 64 blocks x 256 threads is trivially
// co-resident on 256 CUs.

#define DD 512
#define BB 16
#define OO 64
#define NC 8
#define MAGIC1 0x13579BDFu
#define MAGIC2 0x2468ACE1u

__device__ __forceinline__ void barrier_all(unsigned* flags, unsigned magic) {
  __syncthreads();
  if (threadIdx.x == 0)
    __hip_atomic_store(&flags[blockIdx.x], magic, __ATOMIC_RELEASE,
                       __HIP_MEMORY_SCOPE_AGENT);
  if (threadIdx.x < 64) {
    while (__hip_atomic_load(&flags[threadIdx.x], __ATOMIC_ACQUIRE,
                             __HIP_MEMORY_SCOPE_AGENT) != magic) {
      __builtin_amdgcn_s_sleep(1);
    }
  }
  __syncthreads();
}

__global__ __launch_bounds__(256) void k_fused(
    const float* __restrict__ cb,     // context_batch  [B,2]
    const float* __restrict__ cw,     // ctx_w          [2,D]
    const float* __restrict__ cbias,  // ctx_b          [D]
    const float* __restrict__ wv,     // ca_wv          [D,D]
    const float* __restrict__ bv,     // ca_bv          [D]
    const float* __restrict__ wo,     // ca_wo          [D,D]
    const float* __restrict__ bo,     // ca_bo          [D]
    const int*   __restrict__ sid,    // specialist_ids [B]
    const float* __restrict__ pw,     // pred_w         [NS,D,OUT]
    const float* __restrict__ pb,     // pred_b         [NS,OUT]
    const float* __restrict__ aw,     // act_w          [NS,D,OUT]
    const float* __restrict__ ab,     // act_b          [NS,OUT]
    float* ws, float* __restrict__ out) {
  __shared__ float cs[BB * 64];        // 4 KB  (phase C reuses as last[512])
  __shared__ float red[4 * BB * 64];   // 16 KB (phase C reuses as head partials)

  float*    vpart = ws;                       // [NC][BB][DD]
  float*    lpart = ws + NC * BB * DD;        // [NC][BB][DD]
  unsigned* f1 = reinterpret_cast<unsigned*>(ws + 2 * NC * BB * DD);
  unsigned* f2 = f1 + 64;

  const int tid = threadIdx.x;
  const int bid = blockIdx.x;
  const int jb = bid & 7, db = bid >> 3;
  const int d0 = db * 64, j0 = jb * 64;
  const int j = tid & 63, dsub4 = tid >> 6;   // 4 x 16-d split for phases A/B

  // ---------------- phase A: vpart[db][b][j0+j] ----------------
  for (int idx = tid; idx < BB * 64; idx += 256) {
    const int b = idx >> 6, d = idx & 63;
    cs[idx] = fmaf(cb[2 * b], cw[d0 + d],
               fmaf(cb[2 * b + 1], cw[DD + d0 + d], cbias[d0 + d]));
  }
  __syncthreads();
  {
    float wr[16];
#pragma unroll
    for (int i = 0; i < 16; ++i)
      wr[i] = wv[(d0 + dsub4 * 16 + i) * DD + j0 + j];
    float acc[BB];
#pragma unroll
    for (int b = 0; b < BB; ++b) acc[b] = 0.f;
#pragma unroll
    for (int i = 0; i < 16; ++i) {
      const int d = dsub4 * 16 + i;
#pragma unroll
      for (int b = 0; b < BB; ++b) acc[b] = fmaf(cs[b * 64 + d], wr[i], acc[b]);
    }
#pragma unroll
    for (int b = 0; b < BB; ++b) red[dsub4 * (BB * 64) + b * 64 + j] = acc[b];
  }
  __syncthreads();
  for (int idx = tid; idx < BB * 64; idx += 256) {
    const float s = red[idx] + red[idx + BB * 64] +
                    red[idx + 2 * BB * 64] + red[idx + 3 * BB * 64];
    vpart[(db * BB + (idx >> 6)) * DD + j0 + (idx & 63)] = s;
  }

  barrier_all(f1, MAGIC1);

  // ---------------- phase B: lpart[db][b][j0+j] ----------------
  for (int idx = tid; idx < BB * 64; idx += 256) {
    const int b = idx >> 6, d = idx & 63;
    float s = bv[d0 + d];
#pragma unroll
    for (int c = 0; c < NC; ++c) s += vpart[(c * BB + b) * DD + d0 + d];
    cs[idx] = s;
  }
  __syncthreads();
  {
    float wr[16];
#pragma unroll
    for (int i = 0; i < 16; ++i)
      wr[i] = wo[(d0 + dsub4 * 16 + i) * DD + j0 + j];
    float acc[BB];
#pragma unroll
    for (int b = 0; b < BB; ++b) acc[b] = 0.f;
#pragma unroll
    for (int i = 0; i < 16; ++i) {
      const int d = dsub4 * 16 + i;
#pragma unroll
      for (int b = 0; b < BB; ++b) acc[b] = fmaf(cs[b * 64 + d], wr[i], acc[b]);
    }
#pragma unroll
    for (int b = 0; b < BB; ++b) red[dsub4 * (BB * 64) + b * 64 + j] = acc[b];
  }
  __syncthreads();
  for (int idx = tid; idx < BB * 64; idx += 256) {
    const float s = red[idx] + red[idx + BB * 64] +
                    red[idx + 2 * BB * 64] + red[idx + 3 * BB * 64];
    lpart[(db * BB + (idx >> 6)) * DD + j0 + (idx & 63)] = s;
  }

  barrier_all(f2, MAGIC2);

  // ---------------- phase C: heads (blocks 0..31) ----------------
  if (bid >= 32) return;
  const int b = bid & 15, half = bid >> 4;
  float* ls = cs;     // 512 floats
  float* rc = red;    // 16*64 floats
  for (int d = tid; d < DD; d += 256) {
    float s = bo[d];
#pragma unroll
    for (int c = 0; c < NC; ++c) s += lpart[(c * BB + b) * DD + d];
    ls[d] = s;
  }
  __syncthreads();
  {
    const int s = sid[b];
    const int og = tid & 15, dp = tid >> 4;   // dp in [0,16), 32 d each
    const float4* w4 =
        reinterpret_cast<const float4*>((half ? aw : pw) + s * DD * OO) +
        dp * 32 * 16 + og;
    float4 acc = {0.f, 0.f, 0.f, 0.f};
#pragma unroll
    for (int i = 0; i < 32; ++i) {
      const float c = ls[dp * 32 + i];
      const float4 wr = w4[i * 16];
      acc.x = fmaf(c, wr.x, acc.x);
      acc.y = fmaf(c, wr.y, acc.y);
      acc.z = fmaf(c, wr.z, acc.z);
      acc.w = fmaf(c, wr.w, acc.w);
    }
    reinterpret_cast<float4*>(rc)[dp * 16 + og] = acc;
  }
  __syncthreads();
  if (tid < OO) {
    float a = (half ? ab : pb)[sid[b] * OO + tid];
#pragma unroll
    for (int p = 0; p < 16; ++p) a += rc[p * 64 + tid];
    out[half * (BB * OO) + b * OO + tid] = a;
  }
}

extern "C" void kernel_launch(void* const* d_in, const int* in_sizes, int n_in,
                              void* d_out, int out_size, void* d_ws, size_t ws_size,
                              hipStream_t stream) {
  // setup_inputs() order:
  // 0 x_batch 1 context_batch 2 specialist_ids 3 emb_table 4 wqkv 5 bqkv 6 wo 7 bo
  // 8 ln1_g 9 ln1_b 10 w1 11 b1 12 w2 13 b2 14 ln2_g 15 ln2_b 16 ctx_w 17 ctx_b
  // 18 ca_wq 19 ca_bq 20 ca_wk 21 ca_bk 22 ca_wv 23 ca_bv 24 ca_wo 25 ca_bo
  // 26 pred_w 27 pred_b 28 act_w 29 act_b
  k_fused<<<64, 256, 0, stream>>>(
      reinterpret_cast<const float*>(d_in[1]),
      reinterpret_cast<const float*>(d_in[16]),
      reinterpret_cast<const float*>(d_in[17]),
      reinterpret_cast<const float*>(d_in[22]),
      reinterpret_cast<const float*>(d_in[23]),
      reinterpret_cast<const float*>(d_in[24]),
      reinterpret_cast<const float*>(d_in[25]),
      reinterpret_cast<const int*>(d_in[2]),
      reinterpret_cast<const float*>(d_in[26]),
      reinterpret_cast<const float*>(d_in[27]),
      reinterpret_cast<const float*>(d_in[28]),
      reinterpret_cast<const float*>(d_in[29]),
      reinterpret_cast<float*>(d_ws),
      reinterpret_cast<float*>(d_out));
}

// Round 6
// 146.809 us; speedup vs baseline: 1.0190x; 1.0190x over previous
//
#include <hip/hip_runtime.h>
#include <hip/hip_bf16.h>

// Dead-code-eliminated + rank-2-factorized forward (passed rounds 1-5, absmax <= 4e-6).
// Cross-attention has ONE key/value -> softmax == 1, so outputs depend only on the
// ctx -> v -> last -> heads chain. Further: ctx[b] = c0[b]*cw[0] + c1[b]*cw[1] + ctx_b
// is rank-2+const in b, and every downstream op is linear in ctx. So compute three
// batch-INDEPENDENT vectors through the chain:
//   u_k = r_k @ ca_wv   (r = {cw[0], cw[1], ctx_b}),  u_2 += ca_bv
//   t_k = u_k @ ca_wo,                                t_2 += ca_bo
//   P_k[s,head] = t_k @ W[s,head],                    P_2 += bias[s,head]
//   out[b] = c0[b]*P0[sid[b]] + c1[b]*P1[sid[b]] + P2[sid[b]]
// Batch (16) drops out of all heavy work. Three stream-ordered dispatches
// (round-5 lesson: in-kernel grid barriers cost MORE than dispatch gaps),
// weight-stationary, partial sums through d_ws, deterministic reductions.

#define DD 512
#define BB 16
#define OO 64

// ---- K1: upart[db][k][j] = sum_{d in db-chunk} r_k[d] * wv[d][j] ----
// grid 64 = (jb 8 x db 8), 256 threads = (dsub 4 x j 64)
__global__ __launch_bounds__(256) void k1_u(
    const float* __restrict__ cw, const float* __restrict__ cbias,
    const float* __restrict__ wv, float* __restrict__ upart) {
  __shared__ float rs[3][64];
  __shared__ float red[4][3][64];
  const int tid = threadIdx.x;
  const int jb = blockIdx.x & 7, db = blockIdx.x >> 3;
  const int d0 = db * 64, j0 = jb * 64;

  if (tid < 64) {
    rs[0][tid] = cw[d0 + tid];
    rs[1][tid] = cw[DD + d0 + tid];
    rs[2][tid] = cbias[d0 + tid];
  }
  __syncthreads();

  const int j = tid & 63, ds = tid >> 6;
  float a0 = 0.f, a1 = 0.f, a2 = 0.f;
#pragma unroll
  for (int i = 0; i < 16; ++i) {
    const int d = ds * 16 + i;
    const float w = wv[(d0 + d) * DD + j0 + j];
    a0 = fmaf(rs[0][d], w, a0);
    a1 = fmaf(rs[1][d], w, a1);
    a2 = fmaf(rs[2][d], w, a2);
  }
  red[ds][0][j] = a0; red[ds][1][j] = a1; red[ds][2][j] = a2;
  __syncthreads();
  if (tid < 192) {
    const int k = tid >> 6, jj = tid & 63;
    const float s = red[0][k][jj] + red[1][k][jj] + red[2][k][jj] + red[3][k][jj];
    upart[(db * 3 + k) * DD + j0 + jj] = s;
  }
}

// ---- K2: tpart[db][k][j] = sum_{d in db-chunk} u_k[d] * wo[d][j] ----
// u_k[d] = (k==2 ? bv[d] : 0) + sum_db upart[db][k][d]
__global__ __launch_bounds__(256) void k2_t(
    const float* __restrict__ bv, const float* __restrict__ wo,
    const float* __restrict__ upart, float* __restrict__ tpart) {
  __shared__ float us[3][64];
  __shared__ float red[4][3][64];
  const int tid = threadIdx.x;
  const int jb = blockIdx.x & 7, db = blockIdx.x >> 3;
  const int d0 = db * 64, j0 = jb * 64;

  if (tid < 192) {
    const int k = tid >> 6, d = tid & 63;
    float s = (k == 2) ? bv[d0 + d] : 0.f;
#pragma unroll
    for (int c = 0; c < 8; ++c) s += upart[(c * 3 + k) * DD + d0 + d];
    us[k][d] = s;
  }
  __syncthreads();

  const int j = tid & 63, ds = tid >> 6;
  float a0 = 0.f, a1 = 0.f, a2 = 0.f;
#pragma unroll
  for (int i = 0; i < 16; ++i) {
    const int d = ds * 16 + i;
    const float w = wo[(d0 + d) * DD + j0 + j];
    a0 = fmaf(us[0][d], w, a0);
    a1 = fmaf(us[1][d], w, a1);
    a2 = fmaf(us[2][d], w, a2);
  }
  red[ds][0][j] = a0; red[ds][1][j] = a1; red[ds][2][j] = a2;
  __syncthreads();
  if (tid < 192) {
    const int k = tid >> 6, jj = tid & 63;
    const float s = red[0][k][jj] + red[1][k][jj] + red[2][k][jj] + red[3][k][jj];
    tpart[(db * 3 + k) * DD + j0 + jj] = s;
  }
}

// ---- K3: heads. grid 16 = (s 4 x head 2 x ohalf 2), 256 threads = (dp 8 x o 32) ----
// t_k[d] = (k==2 ? bo[d] : 0) + sum_db tpart[db][k][d]
// P_k[o] = sum_d t_k[d] * W[s][d][o0+o];  P_2 += bias
// out[b][o0+o] = c0[b]*P0[o] + c1[b]*P1[o] + P2[o]  for b with sid[b]==s
__global__ __launch_bounds__(256) void k3_head(
    const float* __restrict__ bo, const float* __restrict__ tpart,
    const int* __restrict__ sid, const float* __restrict__ cb,
    const float* __restrict__ pw, const float* __restrict__ pb,
    const float* __restrict__ aw, const float* __restrict__ ab,
    float* __restrict__ out) {
  __shared__ float ts[3][DD];      // 6 KB
  __shared__ float red[8][3][32];
  __shared__ float P[3][32];
  const int tid = threadIdx.x;
  const int s = blockIdx.x & 3, head = (blockIdx.x >> 2) & 1, oh = blockIdx.x >> 3;
  const int o0 = oh * 32;

  for (int idx = tid; idx < 3 * DD; idx += 256) {
    const int k = idx >> 9, d = idx & (DD - 1);
    float v = (k == 2) ? bo[d] : 0.f;
#pragma unroll
    for (int c = 0; c < 8; ++c) v += tpart[(c * 3 + k) * DD + d];
    ts[k][d] = v;
  }
  __syncthreads();

  const int o = tid & 31, dp = tid >> 5;
  const float* W = (head ? aw : pw) + s * DD * OO;
  float a0 = 0.f, a1 = 0.f, a2 = 0.f;
#pragma unroll 16
  for (int i = 0; i < 64; ++i) {
    const int d = dp * 64 + i;
    const float w = W[d * OO + o0 + o];
    a0 = fmaf(ts[0][d], w, a0);
    a1 = fmaf(ts[1][d], w, a1);
    a2 = fmaf(ts[2][d], w, a2);
  }
  red[dp][0][o] = a0; red[dp][1][o] = a1; red[dp][2][o] = a2;
  __syncthreads();
  if (tid < 96) {
    const int k = tid >> 5, oo = tid & 31;
    float a = 0.f;
#pragma unroll
    for (int p = 0; p < 8; ++p) a += red[p][k][oo];
    if (k == 2) a += (head ? ab : pb)[s * OO + o0 + oo];
    P[k][oo] = a;
  }
  __syncthreads();
  if (tid < 32) {
#pragma unroll
    for (int b = 0; b < BB; ++b) {
      if (sid[b] == s) {
        out[head * (BB * OO) + b * OO + o0 + tid] =
            fmaf(cb[2 * b], P[0][tid], fmaf(cb[2 * b + 1], P[1][tid], P[2][tid]));
      }
    }
  }
}

extern "C" void kernel_launch(void* const* d_in, const int* in_sizes, int n_in,
                              void* d_out, int out_size, void* d_ws, size_t ws_size,
                              hipStream_t stream) {
  // setup_inputs() order:
  // 0 x_batch 1 context_batch 2 specialist_ids 3 emb_table 4 wqkv 5 bqkv 6 wo 7 bo
  // 8 ln1_g 9 ln1_b 10 w1 11 b1 12 w2 13 b2 14 ln2_g 15 ln2_b 16 ctx_w 17 ctx_b
  // 18 ca_wq 19 ca_bq 20 ca_wk 21 ca_bk 22 ca_wv 23 ca_bv 24 ca_wo 25 ca_bo
  // 26 pred_w 27 pred_b 28 act_w 29 act_b
  const float* cb    = reinterpret_cast<const float*>(d_in[1]);
  const int*   sid   = reinterpret_cast<const int*>(d_in[2]);
  const float* cw    = reinterpret_cast<const float*>(d_in[16]);
  const float* cbias = reinterpret_cast<const float*>(d_in[17]);
  const float* wv    = reinterpret_cast<const float*>(d_in[22]);
  const float* bv    = reinterpret_cast<const float*>(d_in[23]);
  const float* wo    = reinterpret_cast<const float*>(d_in[24]);
  const float* bo    = reinterpret_cast<const float*>(d_in[25]);
  const float* pw    = reinterpret_cast<const float*>(d_in[26]);
  const float* pb    = reinterpret_cast<const float*>(d_in[27]);
  const float* aw    = reinterpret_cast<const float*>(d_in[28]);
  const float* ab    = reinterpret_cast<const float*>(d_in[29]);

  float* upart = reinterpret_cast<float*>(d_ws);   // [8][3][512]
  float* tpart = upart + 8 * 3 * DD;               // [8][3][512]

  k1_u   <<<64, 256, 0, stream>>>(cw, cbias, wv, upart);
  k2_t   <<<64, 256, 0, stream>>>(bv, wo, upart, tpart);
  k3_head<<<16, 256, 0, stream>>>(bo, tpart, sid, cb, pw, pb, aw, ab,
                                  reinterpret_cast<float*>(d_out));
}

// Round 7
// 144.947 us; speedup vs baseline: 1.0321x; 1.0128x over previous
//
#include <hip/hip_runtime.h>
#include <hip/hip_bf16.h>

// Dead-code-eliminated + rank-2-factorized forward (passed rounds 1-6; absmax 0.0).
// Cross-attention has ONE key/value -> softmax == 1, so outputs depend only on the
// ctx -> v -> last -> heads chain; ctx[b] is rank-2+const in b and the chain is
// linear, so push three batch-independent vectors r = {cw[0], cw[1], ctx_b}:
//   u_k = r_k @ ca_wv  (+ ca_bv for k=2)
//   t_k = u_k @ ca_wo  (+ ca_bo for k=2)
//   P_k = t_k @ W[s,head]  (+ bias for k=2)
//   out[b] = c0[b]*P0[sid[b]] + c1[b]*P1[sid[b]] + P2[sid[b]]
//
// Round-7: TWO dispatches (was 3). Rounds 4 vs 6 showed kernel work is no longer
// measurable (5x FLOP cut -> +2.7us); the controllable residual is per-dispatch
// overhead. kA fuses u-compute + t-partials: block (eb,jb) reads wv[:, e-chunk]
// (128 KB) to form u_k on-chip, then wo[e-chunk, j-chunk] (16 KB) for tpart.
// eb is the fast block index so the 8 jb-duplicates of each e-chunk land on the
// same XCD (bid mod 8) and dedup in its L2. Round-5 lesson stands: no in-kernel
// grid barriers (cost more than dispatch gaps).

#define DD 512
#define BB 16
#define OO 64

// ---- kA: tpart[eb][k][j0+j] = sum_{e in eb-chunk} u_k[e] * wo[e][j0+j] ----
// grid 64 = (eb 8 fast x jb 8), 256 threads
__global__ __launch_bounds__(256) void kA(
    const float* __restrict__ cw, const float* __restrict__ cbias,
    const float* __restrict__ wv, const float* __restrict__ bv,
    const float* __restrict__ wo, float* __restrict__ tpart) {
  __shared__ float rs[3][DD];        // 6 KB: r_k over full d
  __shared__ float red[4][3][64];
  __shared__ float us[3][64];
  const int tid = threadIdx.x;
  const int eb = blockIdx.x & 7, jb = blockIdx.x >> 3;
  const int e0 = eb * 64, j0 = jb * 64;

  for (int idx = tid; idx < DD; idx += 256) {
    rs[0][idx] = cw[idx];
    rs[1][idx] = cw[DD + idx];
    rs[2][idx] = cbias[idx];
  }
  __syncthreads();

  // step 1: u_k over this 64-wide e-chunk (full 512-d sum, 4-way split)
  {
    const int e = tid & 63, ds = tid >> 6;   // ds in [0,4), 128 d each
    const float* wp = wv + e0 + e;
    float a0 = 0.f, a1 = 0.f, a2 = 0.f;
#pragma unroll 16
    for (int i = 0; i < 128; ++i) {
      const int d = ds * 128 + i;
      const float w = wp[d * DD];            // wave: 64 consecutive e -> 256B/row
      a0 = fmaf(rs[0][d], w, a0);            // LDS broadcast (wave-uniform d)
      a1 = fmaf(rs[1][d], w, a1);
      a2 = fmaf(rs[2][d], w, a2);
    }
    red[ds][0][e] = a0; red[ds][1][e] = a1; red[ds][2][e] = a2;
  }
  __syncthreads();
  if (tid < 192) {
    const int k = tid >> 6, e = tid & 63;
    float s = red[0][k][e] + red[1][k][e] + red[2][k][e] + red[3][k][e];
    if (k == 2) s += bv[e0 + e];
    us[k][e] = s;
  }
  __syncthreads();

  // step 2: t-partials for this (e-chunk, j-chunk)
  {
    const int j = tid & 63, es = tid >> 6;   // es in [0,4), 16 e each
    float a0 = 0.f, a1 = 0.f, a2 = 0.f;
#pragma unroll
    for (int i = 0; i < 16; ++i) {
      const int e = es * 16 + i;
      const float w = wo[(e0 + e) * DD + j0 + j];
      a0 = fmaf(us[0][e], w, a0);
      a1 = fmaf(us[1][e], w, a1);
      a2 = fmaf(us[2][e], w, a2);
    }
    red[es][0][j] = a0; red[es][1][j] = a1; red[es][2][j] = a2;
  }
  __syncthreads();
  if (tid < 192) {
    const int k = tid >> 6, j = tid & 63;
    tpart[(eb * 3 + k) * DD + j0 + j] =
        red[0][k][j] + red[1][k][j] + red[2][k][j] + red[3][k][j];
  }
}

// ---- kB: heads. grid 16 = (s 4 x head 2 x oh 2), 256 threads = (dp 8 x o 32) ----
// t_k[d] = (k==2 ? bo[d] : 0) + sum_eb tpart[eb][k][d]
// P_k[o] = sum_d t_k[d] * W[s][d][o0+o];  P_2 += bias
// out[b][o0+o] = c0[b]*P0[o] + c1[b]*P1[o] + P2[o]  for b with sid[b]==s
__global__ __launch_bounds__(256) void kB(
    const float* __restrict__ bo, const float* __restrict__ tpart,
    const int* __restrict__ sid, const float* __restrict__ cb,
    const float* __restrict__ pw, const float* __restrict__ pb,
    const float* __restrict__ aw, const float* __restrict__ ab,
    float* __restrict__ out) {
  __shared__ float ts[3][DD];      // 6 KB
  __shared__ float red[8][3][32];
  __shared__ float P[3][32];
  const int tid = threadIdx.x;
  const int s = blockIdx.x & 3, head = (blockIdx.x >> 2) & 1, oh = blockIdx.x >> 3;
  const int o0 = oh * 32;

  for (int idx = tid; idx < 3 * DD; idx += 256) {
    const int k = idx >> 9, d = idx & (DD - 1);
    float v = (k == 2) ? bo[d] : 0.f;
#pragma unroll
    for (int c = 0; c < 8; ++c) v += tpart[(c * 3 + k) * DD + d];
    ts[k][d] = v;
  }
  __syncthreads();

  const int o = tid & 31, dp = tid >> 5;
  const float* W = (head ? aw : pw) + s * DD * OO;
  float a0 = 0.f, a1 = 0.f, a2 = 0.f;
#pragma unroll 16
  for (int i = 0; i < 64; ++i) {
    const int d = dp * 64 + i;
    const float w = W[d * OO + o0 + o];
    a0 = fmaf(ts[0][d], w, a0);
    a1 = fmaf(ts[1][d], w, a1);
    a2 = fmaf(ts[2][d], w, a2);
  }
  red[dp][0][o] = a0; red[dp][1][o] = a1; red[dp][2][o] = a2;
  __syncthreads();
  if (tid < 96) {
    const int k = tid >> 5, oo = tid & 31;
    float a = 0.f;
#pragma unroll
    for (int p = 0; p < 8; ++p) a += red[p][k][oo];
    if (k == 2) a += (head ? ab : pb)[s * OO + o0 + oo];
    P[k][oo] = a;
  }
  __syncthreads();
  if (tid < 32) {
#pragma unroll
    for (int b = 0; b < BB; ++b) {
      if (sid[b] == s) {
        out[head * (BB * OO) + b * OO + o0 + tid] =
            fmaf(cb[2 * b], P[0][tid], fmaf(cb[2 * b + 1], P[1][tid], P[2][tid]));
      }
    }
  }
}

extern "C" void kernel_launch(void* const* d_in, const int* in_sizes, int n_in,
                              void* d_out, int out_size, void* d_ws, size_t ws_size,
                              hipStream_t stream) {
  // setup_inputs() order:
  // 0 x_batch 1 context_batch 2 specialist_ids 3 emb_table 4 wqkv 5 bqkv 6 wo 7 bo
  // 8 ln1_g 9 ln1_b 10 w1 11 b1 12 w2 13 b2 14 ln2_g 15 ln2_b 16 ctx_w 17 ctx_b
  // 18 ca_wq 19 ca_bq 20 ca_wk 21 ca_bk 22 ca_wv 23 ca_bv 24 ca_wo 25 ca_bo
  // 26 pred_w 27 pred_b 28 act_w 29 act_b
  const float* cb    = reinterpret_cast<const float*>(d_in[1]);
  const int*   sid   = reinterpret_cast<const int*>(d_in[2]);
  const float* cw    = reinterpret_cast<const float*>(d_in[16]);
  const float* cbias = reinterpret_cast<const float*>(d_in[17]);
  const float* wv    = reinterpret_cast<const float*>(d_in[22]);
  const float* bv    = reinterpret_cast<const float*>(d_in[23]);
  const float* wo    = reinterpret_cast<const float*>(d_in[24]);
  const float* bo    = reinterpret_cast<const float*>(d_in[25]);
  const float* pw    = reinterpret_cast<const float*>(d_in[26]);
  const float* pb    = reinterpret_cast<const float*>(d_in[27]);
  const float* aw    = reinterpret_cast<const float*>(d_in[28]);
  const float* ab    = reinterpret_cast<const float*>(d_in[29]);

  float* tpart = reinterpret_cast<float*>(d_ws);   // [8][3][512]

  kA<<<64, 256, 0, stream>>>(cw, cbias, wv, bv, wo, tpart);
  kB<<<16, 256, 0, stream>>>(bo, tpart, sid, cb, pw, pb, aw, ab,
                             reinterpret_cast<float*>(d_out));
}